// Round 13
// baseline (125.728 us; speedup 1.0000x reference)
//
#include <hip/hip_runtime.h>

typedef _Float16 f16x8  __attribute__((ext_vector_type(8)));
typedef _Float16 f16x4  __attribute__((ext_vector_type(4)));
typedef _Float16 f16x2  __attribute__((ext_vector_type(2)));
typedef float    f32x4  __attribute__((ext_vector_type(4)));
typedef float    f32x16 __attribute__((ext_vector_type(16)));
typedef int      i32x2  __attribute__((ext_vector_type(2)));

#define MFMA32(a, b, c) __builtin_amdgcn_mfma_f32_32x32x16_f16((a), (b), (c), 0, 0, 0)

static constexpr int SEQ   = 2048;
static constexpr int DIM   = 128;
static constexpr int QBLK  = 128;          // 4 waves x 32 q-rows
static constexpr int KVBLK = 64;           // kv rows per tile (2 x 32 sub-tiles)
static constexpr int NKT   = SEQ / KVBLK;  // 32
static constexpr int BH    = 2 * 16;
static constexpr int KSTR  = 136;          // K LDS row stride (f16), 272B padded
static constexpr int VSTR  = 72;           // Vt LDS row stride (f16), 144B padded

// o = exp(QK^T - rowmax) @ V  (unnormalized, fp32 in/out)
// r12 core + KVBLK=64 (half the barriers; two independent 8-deep QK chains)
// + speculative P (exp2 with old max runs parallel to the max tree; rare
// exact fixup when the running max grows by > THR).
__global__ __launch_bounds__(256, 2)
void fa_fwd_kernel(const float* __restrict__ Qg, const float* __restrict__ Kg,
                   const float* __restrict__ Vg, float* __restrict__ Og)
{
    __shared__ __align__(16) _Float16 Ksh[2][KVBLK * KSTR];   // 2 x 17408 B
    __shared__ __align__(16) _Float16 Vt[2][DIM * VSTR];      // 2 x 18432 B

    const int tid  = threadIdx.x;
    const int wv   = tid >> 6;
    const int lane = tid & 63;
    const int lq   = lane & 31;   // q column (and K A-row) owned by this lane
    const int lh   = lane >> 5;   // half: 0/1

    // XCD swizzle: all 16 q-tiles of one bh -> one XCD (K/V L2-resident)
    const int bi = blockIdx.x;
    const int bh = (bi & 7) + 8 * (bi >> 7);
    const int qt = (bi >> 3) & 15;

    const size_t base = (size_t)bh * SEQ * DIM;
    const float* Qp = Qg + base;
    const float* Kp = Kg + base;
    const float* Vp = Vg + base;
    float*       Op = Og + base;

    const int q0 = qt * QBLK + wv * 32;

    // ---- Q fragment (B-operand: col q = lq, elems d = 16t + 8*lh + j), x log2(e)
    constexpr float LOG2E = 1.44269504088896340736f;
    f16x8 qh[8];
    {
        const float* qs = Qp + (size_t)(q0 + lq) * DIM + 8 * lh;
#pragma unroll
        for (int t = 0; t < 8; ++t) {
            const float4 a = *(const float4*)(qs + 16 * t);
            const float4 b = *(const float4*)(qs + 16 * t + 4);
            float xs[8] = {a.x, a.y, a.z, a.w, b.x, b.y, b.z, b.w};
            f16x8 h;
#pragma unroll
            for (int e = 0; e < 8; ++e) h[e] = (_Float16)(xs[e] * LOG2E);
            qh[t] = h;
        }
    }

    // O^T accumulators: acc[dm][r] = O^T[d = 32*dm + (r&3)+8*(r>>2)+4*lh][q = lq]
    f32x16 acc[4];
#pragma unroll
    for (int a = 0; a < 4; ++a)
#pragma unroll
        for (int r = 0; r < 16; ++r) acc[a][r] = 0.0f;

    float mrow  = -3.0e38f;   // running (deferred) max, log2 units
    float mtrue = -3.0e38f;   // true running max, log2 units

    // staging maps (all static register indexing; r8-verified conflict behavior)
    const int ksr = tid >> 2, kc0 = (tid & 3) * 32;   // K: 4 threads/row, 32 floats
    const int vc  = tid & 31;                         // V: d cols {vc,+32,+64,+96}
    const int vk  = (tid >> 5) * 8;                   //    x 8 consecutive k rows
    const float* kb = Kp + (size_t)ksr * DIM + kc0;
    const float* vb = Vp + (size_t)vk * DIM + vc;

    float4 kreg[8];
    float  vreg[4][8];   // [d-col j][k-row r] — static indexing only

    auto stage = [&](int b) {
#pragma unroll
        for (int g = 0; g < 4; ++g) {
            float xs[8] = {kreg[2*g].x, kreg[2*g].y, kreg[2*g].z, kreg[2*g].w,
                           kreg[2*g+1].x, kreg[2*g+1].y, kreg[2*g+1].z, kreg[2*g+1].w};
            f16x8 h;
#pragma unroll
            for (int e = 0; e < 8; ++e) h[e] = (_Float16)xs[e];
            *(f16x8*)((char*)&Ksh[b][0] + (ksr * KSTR + kc0 + 8 * g) * 2) = h;
        }
#pragma unroll
        for (int j = 0; j < 4; ++j) {
            f16x8 h;
#pragma unroll
            for (int r = 0; r < 8; ++r) h[r] = (_Float16)vreg[j][r];
            const int d = vc + 32 * j;
            *(f16x8*)((char*)&Vt[b][0] + (d * VSTR + vk) * 2) = h;
        }
    };
    auto loadT = [&](int t) {
        const float* ks_ = kb + (size_t)t * KVBLK * DIM;
        const float* vs_ = vb + (size_t)t * KVBLK * DIM;
#pragma unroll
        for (int u = 0; u < 8; ++u) kreg[u] = *(const float4*)(ks_ + u * 4);
#pragma unroll
        for (int j = 0; j < 4; ++j)
#pragma unroll
            for (int r = 0; r < 8; ++r) vreg[j][r] = vs_[(size_t)r * DIM + 32 * j];
    };

    // prologue: tile 0 staged; tile 1 in regs
    loadT(0);
    stage(0);
    loadT(1);

    for (int kt = 0; kt < NKT; ++kt) {
        const int cur = kt & 1;
        __syncthreads();   // buf[cur] writes visible; buf[cur^1] readers done

        if (kt + 1 < NKT) stage(cur ^ 1);    // tile kt+1 (regs loaded last iter)
        if (kt + 2 < NKT) loadT(kt + 2);     // issue tile kt+2 loads
        __builtin_amdgcn_sched_barrier(0);   // pin load issue here

        // ---- S^T = K Q^T: two independent 8-deep chains (k-sub 0 / k-sub 1)
        const char* Kc = (const char*)&Ksh[cur][0];
        const char* Vc = (const char*)&Vt[cur][0];
        f32x16 s0, s1;
#pragma unroll
        for (int r = 0; r < 16; ++r) { s0[r] = 0.0f; s1[r] = 0.0f; }
        __builtin_amdgcn_s_setprio(1);
#pragma unroll
        for (int t = 0; t < 8; ++t) {
            f16x8 ka = *(const f16x8*)(Kc + (lq * KSTR + 16 * t + 8 * lh) * 2);
            f16x8 kc = *(const f16x8*)(Kc + ((lq + 32) * KSTR + 16 * t + 8 * lh) * 2);
            s0 = MFMA32(ka, qh[t], s0);
            s1 = MFMA32(kc, qh[t], s1);
        }
        __builtin_amdgcn_s_setprio(0);
        // s0[r] = S'^T[k=(r&3)+8*(r>>2)+4*lh][q=lq]; s1: k+32  (log2 units)

        // ---- speculative P with OLD mrow (parallel to the max tree below)
        int pk[16];
#pragma unroll
        for (int i = 0; i < 8; ++i) {
            f16x2 e0 = {(_Float16)__builtin_exp2f(s0[2*i]   - mrow),
                        (_Float16)__builtin_exp2f(s0[2*i+1] - mrow)};
            f16x2 e1 = {(_Float16)__builtin_exp2f(s1[2*i]   - mrow),
                        (_Float16)__builtin_exp2f(s1[2*i+1] - mrow)};
            pk[i]     = __builtin_bit_cast(int, e0);
            pk[8 + i] = __builtin_bit_cast(int, e1);
        }

        // ---- row max over 64 k (max3-friendly tree; halves share q-col via shfl)
        float tmax = fmaxf(s0[0], s1[0]);
#pragma unroll
        for (int r = 1; r < 16; ++r) tmax = fmaxf(tmax, fmaxf(s0[r], s1[r]));
        tmax = fmaxf(tmax, __shfl_xor(tmax, 32));
        mtrue = fmaxf(mtrue, tmax);

        // ---- rare fixup: max grew by > THR -> rescale acc, recompute P exactly
        if (!__all(tmax - mrow <= 6.0f)) {
            const float mn  = fmaxf(mrow, tmax);
            const float scl = __builtin_exp2f(mrow - mn);
            mrow = mn;
#pragma unroll
            for (int a = 0; a < 4; ++a)
#pragma unroll
                for (int r = 0; r < 16; ++r) acc[a][r] *= scl;
#pragma unroll
            for (int i = 0; i < 8; ++i) {
                f16x2 e0 = {(_Float16)__builtin_exp2f(s0[2*i]   - mn),
                            (_Float16)__builtin_exp2f(s0[2*i+1] - mn)};
                f16x2 e1 = {(_Float16)__builtin_exp2f(s1[2*i]   - mn),
                            (_Float16)__builtin_exp2f(s1[2*i+1] - mn)};
                pk[i]     = __builtin_bit_cast(int, e0);
                pk[8 + i] = __builtin_bit_cast(int, e1);
            }
        }

        // ---- PV: O^T += V^T P^T over 4 k-steps (k = 16s + 8lh + j)
        // B-frag via v_permlane32_swap pairs (r12-hardware-verified mapping)
#pragma unroll
        for (int s = 0; s < 4; ++s) {
            const int b  = (s >> 1) * 8;   // words from s0 for s<2, s1 for s>=2
            const int sl = s & 1;
            i32x2 w02 = __builtin_amdgcn_permlane32_swap(pk[b+4*sl+0], pk[b+4*sl+2], false, false);
            i32x2 w13 = __builtin_amdgcn_permlane32_swap(pk[b+4*sl+1], pk[b+4*sl+3], false, false);
            union { int i[4]; f16x8 v; } u;
            u.i[0] = w02[0]; u.i[1] = w13[0]; u.i[2] = w02[1]; u.i[3] = w13[1];
            const f16x8 pb = u.v;
            __builtin_amdgcn_s_setprio(1);
#pragma unroll
            for (int dm = 0; dm < 4; ++dm) {
                const int d = dm * 32 + lq;
                f16x8 va = *(const f16x8*)(Vc + (d * VSTR + 16 * s + 8 * lh) * 2);
                acc[dm] = MFMA32(va, pb, acc[dm]);
            }
            __builtin_amdgcn_s_setprio(0);
        }
    }

    // ---- final correction to the true global row max (reference is unnormalized)
    const float fin = __builtin_exp2f(mrow - mtrue);
#pragma unroll
    for (int a = 0; a < 4; ++a)
#pragma unroll
        for (int r = 0; r < 16; ++r) acc[a][r] *= fin;

    // ---- store O: reg r of acc[dm] -> col d = 32*dm + 8*(r>>2) + 4*lh + (r&3)
    float* ob = Op + (size_t)(q0 + lq) * DIM + 4 * lh;
#pragma unroll
    for (int dm = 0; dm < 4; ++dm)
#pragma unroll
        for (int kp = 0; kp < 4; ++kp) {
            f32x4 v4 = {acc[dm][4*kp], acc[dm][4*kp+1], acc[dm][4*kp+2], acc[dm][4*kp+3]};
            *(f32x4*)(ob + dm * 32 + kp * 8) = v4;
        }
}

extern "C" void kernel_launch(void* const* d_in, const int* in_sizes, int n_in,
                              void* d_out, int out_size, void* d_ws, size_t ws_size,
                              hipStream_t stream) {
    const float* q = (const float*)d_in[0];
    const float* k = (const float*)d_in[1];
    const float* v = (const float*)d_in[2];
    float* o = (float*)d_out;
    dim3 grid((SEQ / QBLK) * BH);   // 512 blocks = 2/CU, XCD-swizzled in-kernel
    fa_fwd_kernel<<<grid, dim3(256), 0, stream>>>(q, k, v, o);
}

// Round 14
// 115.038 us; speedup vs baseline: 1.0929x; 1.0929x over previous
//
#include <hip/hip_runtime.h>

typedef _Float16 f16x8  __attribute__((ext_vector_type(8)));
typedef _Float16 f16x4  __attribute__((ext_vector_type(4)));
typedef _Float16 f16x2  __attribute__((ext_vector_type(2)));
typedef float    f32x4  __attribute__((ext_vector_type(4)));
typedef float    f32x16 __attribute__((ext_vector_type(16)));
typedef int      i32x2  __attribute__((ext_vector_type(2)));

#define MFMA32(a, b, c) __builtin_amdgcn_mfma_f32_32x32x16_f16((a), (b), (c), 0, 0, 0)

static constexpr int SEQ   = 2048;
static constexpr int DIM   = 128;
static constexpr int QBLK  = 128;          // 4 waves x 32 q-rows
static constexpr int KVBLK = 32;           // kv rows per tile (r13: 64 regressed, twice)
static constexpr int NKT   = SEQ / KVBLK;  // 64
static constexpr int BH    = 2 * 16;
static constexpr int KSTR  = 136;          // K LDS row stride (f16), 272B padded
static constexpr int VSTR  = 40;           // Vt LDS row stride (f16), 80B padded

// o = exp(QK^T - rowmax) @ V  (unnormalized, fp32 in/out)
// r12 base (dbuf LDS, 1 barrier/iter, pinned reg prefetch, permlane32 PV)
// + speculative P: exp2(st - mrow_old) issued BEFORE the max tree + shfl,
// removing the softmax serialization from the per-iter chain. Rare exact
// fixup when the running max grows by > THR (always triggers on iter 0).
__global__ __launch_bounds__(256, 2)
void fa_fwd_kernel(const float* __restrict__ Qg, const float* __restrict__ Kg,
                   const float* __restrict__ Vg, float* __restrict__ Og)
{
    __shared__ __align__(16) _Float16 Ksh[2][KVBLK * KSTR];
    __shared__ __align__(16) _Float16 Vt[2][DIM * VSTR];

    const int tid  = threadIdx.x;
    const int wv   = tid >> 6;
    const int lane = tid & 63;
    const int lq   = lane & 31;   // q column (and K A-row) owned by this lane
    const int lh   = lane >> 5;   // half: 0/1

    // XCD swizzle: all 16 q-tiles of one bh -> one XCD (K/V L2-resident)
    const int bi = blockIdx.x;
    const int bh = (bi & 7) + 8 * (bi >> 7);
    const int qt = (bi >> 3) & 15;

    const size_t base = (size_t)bh * SEQ * DIM;
    const float* Qp = Qg + base;
    const float* Kp = Kg + base;
    const float* Vp = Vg + base;
    float*       Op = Og + base;

    const int q0 = qt * QBLK + wv * 32;

    // ---- Q fragment (B-operand: col q = lq, elems d = 16t + 8*lh + j), x log2(e)
    constexpr float LOG2E = 1.44269504088896340736f;
    f16x8 qh[8];
    {
        const float* qs = Qp + (size_t)(q0 + lq) * DIM + 8 * lh;
#pragma unroll
        for (int t = 0; t < 8; ++t) {
            const float4 a = *(const float4*)(qs + 16 * t);
            const float4 b = *(const float4*)(qs + 16 * t + 4);
            float xs[8] = {a.x, a.y, a.z, a.w, b.x, b.y, b.z, b.w};
            f16x8 h;
#pragma unroll
            for (int e = 0; e < 8; ++e) h[e] = (_Float16)(xs[e] * LOG2E);
            qh[t] = h;
        }
    }

    // O^T accumulators: acc[dm][r] = O^T[d = 32*dm + (r&3)+8*(r>>2)+4*lh][q = lq]
    f32x16 acc[4];
#pragma unroll
    for (int a = 0; a < 4; ++a)
#pragma unroll
        for (int r = 0; r < 16; ++r) acc[a][r] = 0.0f;

    float mrow  = -3.0e38f;   // running (deferred) max, log2 units
    float mtrue = -3.0e38f;   // true running max, log2 units

    // staging maps (all static register indexing)
    const int ksr = tid >> 3, kc0 = (tid & 7) * 16;   // K: 8 threads/row, 16 floats
    const int vc  = tid & 31;                         // V: d cols {vc,+32,+64,+96}
    const int vk  = (tid >> 5) * 4;                   //    x 4 consecutive k rows
    const float* kb = Kp + (size_t)ksr * DIM + kc0;
    const float* vb = Vp + (size_t)vk * DIM + vc;

    float4 kreg[4];
    float  vreg[4][4];   // [d-col j][k-row r]

    auto stage = [&](int b) {
#pragma unroll
        for (int g = 0; g < 2; ++g) {
            float xs[8] = {kreg[2*g].x, kreg[2*g].y, kreg[2*g].z, kreg[2*g].w,
                           kreg[2*g+1].x, kreg[2*g+1].y, kreg[2*g+1].z, kreg[2*g+1].w};
            f16x8 h;
#pragma unroll
            for (int e = 0; e < 8; ++e) h[e] = (_Float16)xs[e];
            *(f16x8*)((char*)&Ksh[b][0] + (ksr * KSTR + kc0 + 8 * g) * 2) = h;
        }
#pragma unroll
        for (int j = 0; j < 4; ++j) {
            const int d = vc + 32 * j;
            f16x4 tv = {(_Float16)vreg[j][0], (_Float16)vreg[j][1],
                        (_Float16)vreg[j][2], (_Float16)vreg[j][3]};
            *(f16x4*)((char*)&Vt[b][0] + (d * VSTR + vk) * 2) = tv;
        }
    };
    auto loadT = [&](int t) {
        const float* ks_ = kb + (size_t)t * KVBLK * DIM;
        const float* vs_ = vb + (size_t)t * KVBLK * DIM;
#pragma unroll
        for (int u = 0; u < 4; ++u) kreg[u] = *(const float4*)(ks_ + u * 4);
#pragma unroll
        for (int j = 0; j < 4; ++j)
#pragma unroll
            for (int r = 0; r < 4; ++r) vreg[j][r] = vs_[(size_t)r * DIM + 32 * j];
    };

    // prologue: tile 0 staged; tile 1 in regs
    loadT(0);
    stage(0);
    loadT(1);

    for (int kt = 0; kt < NKT; ++kt) {
        const int cur = kt & 1;
        __syncthreads();   // buf[cur] writes visible; buf[cur^1] readers done

        if (kt + 1 < NKT) stage(cur ^ 1);    // tile kt+1 (regs loaded last iter)
        if (kt + 2 < NKT) loadT(kt + 2);     // issue tile kt+2 loads
        __builtin_amdgcn_sched_barrier(0);   // pin load issue here

        // ---- S^T = K Q^T, single pass, 2 interleaved accumulator chains
        const char* Kc = (const char*)&Ksh[cur][0];
        const char* Vc = (const char*)&Vt[cur][0];
        f32x16 s0, s1;
#pragma unroll
        for (int r = 0; r < 16; ++r) { s0[r] = 0.0f; s1[r] = 0.0f; }
        __builtin_amdgcn_s_setprio(1);
#pragma unroll
        for (int t = 0; t < 4; ++t) {
            f16x8 ka = *(const f16x8*)(Kc + (lq * KSTR + 32 * t + 8 * lh) * 2);
            f16x8 kc = *(const f16x8*)(Kc + (lq * KSTR + 32 * t + 16 + 8 * lh) * 2);
            s0 = MFMA32(ka, qh[2 * t], s0);
            s1 = MFMA32(kc, qh[2 * t + 1], s1);
        }
        __builtin_amdgcn_s_setprio(0);
        f32x16 st = s0 + s1;   // st[r] = S'^T[k = (r&3)+8*(r>>2)+4*lh][q = lq]

        // ---- speculative P with OLD mrow (no dependence on this tile's max)
        int pk[8];
#pragma unroll
        for (int i = 0; i < 8; ++i) {
            f16x2 e = {(_Float16)__builtin_exp2f(st[2 * i] - mrow),
                       (_Float16)__builtin_exp2f(st[2 * i + 1] - mrow)};
            pk[i] = __builtin_bit_cast(int, e);
        }

        // ---- row max (overlaps the exp2 block above in the scheduler)
        float tmax = fmaxf(fmaxf(fmaxf(st[0], st[1]), fmaxf(st[2], st[3])),
                           fmaxf(fmaxf(st[4], st[5]), fmaxf(st[6], st[7])));
        tmax = fmaxf(tmax, fmaxf(fmaxf(fmaxf(st[8], st[9]), fmaxf(st[10], st[11])),
                                 fmaxf(fmaxf(st[12], st[13]), fmaxf(st[14], st[15]))));
        tmax = fmaxf(tmax, __shfl_xor(tmax, 32));
        mtrue = fmaxf(mtrue, tmax);

        // ---- rare fixup: max grew by > THR -> rescale acc, recompute P exactly
        if (!__all(tmax - mrow <= 6.0f)) {
            const float mn  = fmaxf(mrow, tmax);
            const float scl = __builtin_exp2f(mrow - mn);
            mrow = mn;
#pragma unroll
            for (int a = 0; a < 4; ++a)
#pragma unroll
                for (int r = 0; r < 16; ++r) acc[a][r] *= scl;
#pragma unroll
            for (int i = 0; i < 8; ++i) {
                f16x2 e = {(_Float16)__builtin_exp2f(st[2 * i] - mn),
                           (_Float16)__builtin_exp2f(st[2 * i + 1] - mn)};
                pk[i] = __builtin_bit_cast(int, e);
            }
        }

        // ---- PV: O^T += V^T P^T (k = 16s + 8lh + j).
        // B-frag via v_permlane32_swap pairs (r12 hardware-verified mapping)
#pragma unroll
        for (int s = 0; s < 2; ++s) {
            i32x2 w02 = __builtin_amdgcn_permlane32_swap(pk[4*s+0], pk[4*s+2], false, false);
            i32x2 w13 = __builtin_amdgcn_permlane32_swap(pk[4*s+1], pk[4*s+3], false, false);
            union { int i[4]; f16x8 v; } u;
            u.i[0] = w02[0]; u.i[1] = w13[0]; u.i[2] = w02[1]; u.i[3] = w13[1];
            const f16x8 pb = u.v;
            __builtin_amdgcn_s_setprio(1);
#pragma unroll
            for (int dm = 0; dm < 4; ++dm) {
                const int d = dm * 32 + lq;
                f16x8 va = *(const f16x8*)(Vc + (d * VSTR + 16 * s + 8 * lh) * 2);
                acc[dm] = MFMA32(va, pb, acc[dm]);
            }
            __builtin_amdgcn_s_setprio(0);
        }
    }

    // ---- final correction to the true global row max (reference is unnormalized)
    const float fin = __builtin_exp2f(mrow - mtrue);
#pragma unroll
    for (int a = 0; a < 4; ++a)
#pragma unroll
        for (int r = 0; r < 16; ++r) acc[a][r] *= fin;

    // ---- store O: reg r of acc[dm] -> col d = 32*dm + 8*(r>>2) + 4*lh + (r&3)
    float* ob = Op + (size_t)(q0 + lq) * DIM + 4 * lh;
#pragma unroll
    for (int dm = 0; dm < 4; ++dm)
#pragma unroll
        for (int kp = 0; kp < 4; ++kp) {
            f32x4 v4 = {acc[dm][4*kp], acc[dm][4*kp+1], acc[dm][4*kp+2], acc[dm][4*kp+3]};
            *(f32x4*)(ob + dm * 32 + kp * 8) = v4;
        }
}

extern "C" void kernel_launch(void* const* d_in, const int* in_sizes, int n_in,
                              void* d_out, int out_size, void* d_ws, size_t ws_size,
                              hipStream_t stream) {
    const float* q = (const float*)d_in[0];
    const float* k = (const float*)d_in[1];
    const float* v = (const float*)d_in[2];
    float* o = (float*)d_out;
    dim3 grid((SEQ / QBLK) * BH);   // 512 blocks = 2/CU, XCD-swizzled in-kernel
    fa_fwd_kernel<<<grid, dim3(256), 0, stream>>>(q, k, v, o);
}